// Round 11
// baseline (221.042 us; speedup 1.0000x reference)
//
#include <hip/hip_runtime.h>

typedef __attribute__((ext_vector_type(8))) short short8;
typedef __attribute__((ext_vector_type(4))) float f32x4;

// Problem dims
#define BDIM 4096
#define INDIM 1024
#define HDIM 2048
#define KDIM 3072   // IN + H
#define NDIM 8192   // 4*H
#define OUT_HALF 8388608  // 4096*2048
#define NKT 96      // K-tiles of 32
#define ACHUNKS 1572864

__device__ __forceinline__ unsigned short f2bf(float f) {
  unsigned u = __float_as_uint(f);
  u += 0x7FFFu + ((u >> 16) & 1u);
  return (unsigned short)(u >> 16);
}

__device__ __forceinline__ float sigmoidf_(float x) {
  return 1.0f / (1.0f + __expf(-x));
}

// Merged pack: A = [x|h] bf16 [4096][3072]; W' gate-interleaved bf16 [8192][3072];
// bias[n'] = b_ih + b_hh.
__global__ __launch_bounds__(256) void pack_all(
    const float* __restrict__ x, const float* __restrict__ hh,
    const float* __restrict__ w_ih, const float* __restrict__ w_hh,
    const float* __restrict__ b_ih, const float* __restrict__ b_hh,
    unsigned short* __restrict__ A, unsigned short* __restrict__ W,
    float* __restrict__ bias) {
  int idx = blockIdx.x * 256 + threadIdx.x;
  if (idx < ACHUNKS) {
    int m = idx / 384;
    int k0 = (idx - m * 384) * 8;
    const float* src = (k0 < INDIM) ? (x + (size_t)m * INDIM + k0)
                                    : (hh + (size_t)m * HDIM + (k0 - INDIM));
    float4 lo = ((const float4*)src)[0];
    float4 hi = ((const float4*)src)[1];
    union { unsigned short us[8]; uint4 v; } o;
    o.us[0] = f2bf(lo.x); o.us[1] = f2bf(lo.y); o.us[2] = f2bf(lo.z); o.us[3] = f2bf(lo.w);
    o.us[4] = f2bf(hi.x); o.us[5] = f2bf(hi.y); o.us[6] = f2bf(hi.z); o.us[7] = f2bf(hi.w);
    *(uint4*)(A + (size_t)m * KDIM + k0) = o.v;
  } else {
    idx -= ACHUNKS;
    int np = idx / 384;
    int rem = idx - np * 384;
    int k0 = rem * 8;
    int j = np >> 2;
    int g = np & 3;
    int n = g * HDIM + j;
    const float* src = (k0 < INDIM) ? (w_ih + (size_t)n * INDIM + k0)
                                    : (w_hh + (size_t)n * HDIM + (k0 - INDIM));
    float4 lo = ((const float4*)src)[0];
    float4 hi = ((const float4*)src)[1];
    union { unsigned short us[8]; uint4 v; } o;
    o.us[0] = f2bf(lo.x); o.us[1] = f2bf(lo.y); o.us[2] = f2bf(lo.z); o.us[3] = f2bf(lo.w);
    o.us[4] = f2bf(hi.x); o.us[5] = f2bf(hi.y); o.us[6] = f2bf(hi.z); o.us[7] = f2bf(hi.w);
    *(uint4*)(W + (size_t)np * KDIM + k0) = o.v;
    if (rem == 0) bias[np] = b_ih[n] + b_hh[n];
  }
}

__device__ __forceinline__ void gload_lds16(const void* g, void* l) {
  __builtin_amdgcn_global_load_lds(
      (const __attribute__((address_space(1))) void*)g,
      (__attribute__((address_space(3))) void*)l, 16, 0, 0);
}

#define SB0 __builtin_amdgcn_sched_barrier(0)

// 256x256 tile, BK=32, 16 waves (4Mx4N, 1024 thr), per-wave 64x64,
// 4-deep LDS ring (4 x 32KiB), row-pair XOR swizzle (T2), counted vmcnt (T4),
// setprio (T5), R4's 1-barrier-per-K-tile schedule with mi-split clusters.
// 4 waves/SIMD (vs R4's 2) to feed the matrix pipe through read windows.
__global__ __launch_bounds__(1024, 4) void lstm_gemm(
    const unsigned short* __restrict__ A,
    const unsigned short* __restrict__ W,
    const float* __restrict__ bias,
    const float* __restrict__ c,
    float* __restrict__ out) {
  extern __shared__ char smem[];  // 131072 bytes

  const int tid = threadIdx.x;
  const int lane = tid & 63;
  const int wid = tid >> 6;   // 0..15

  // XCD swizzle: xcd owns 2 tm slabs; tn sweeps slowest. Bijective over 512.
  const int bid = blockIdx.x;
  const int local = bid >> 3;
  const int tm = (bid & 7) * 2 + (local & 1);   // 0..15
  const int tn = local >> 1;                    // 0..31

  // ---- staging source decode (inverse swizzle, rule #21) ----
  // Thread stages 16B at region-local P = tid*16 (A) and 16384+tid*16 (B).
  // r2 = tid>>3, cp = tid&7, chunk_log = cp ^ (r2&7).
  const int r2s = tid >> 3;
  const int cgs = (tid & 7) ^ (r2s & 7);
  const int srow = r2s * 2 + (cgs >> 2);    // 0..255
  const int scol = (cgs & 3) * 8;
  const unsigned short* gA = A + (size_t)(tm * 256 + srow) * KDIM + scol;
  const unsigned short* gB = W + (size_t)(tn * 256 + srow) * KDIM + scol;
  const int ldA = tid * 16;
  const int ldB = 16384 + tid * 16;

  // ---- ds_read per-lane constants (swizzled) ----
  const int fr = lane & 15;
  const int fq = lane >> 4;
  const int wm = wid >> 2;    // 0..3 (M quarter)
  const int wn = wid & 3;     // 0..3 (N quarter)
  const int frh = fr >> 1;
  const int clA = (((fr & 1) << 2) | fq) ^ frh;
  const int aconst = wm * 4096 + frh * 128 + clA * 16;            // + mi*1024
  const int bconst = 16384 + wn * 4096 + frh * 128 + clA * 16;    // + ni*1024

  f32x4 acc[4][4] = {};
  short8 af[4], bf_[4];

  // ---- prologue: stage tiles 0,1,2 into bufs 0,1,2 ----
#pragma unroll
  for (int tt = 0; tt < 3; ++tt) {
    char* lb = smem + tt * 32768;
    gload_lds16(gA, lb + ldA);
    gload_lds16(gB, lb + ldB);
    gA += 32; gB += 32;
  }
  asm volatile("s_waitcnt vmcnt(4)" ::: "memory");   // tile 0 landed
  __builtin_amdgcn_s_barrier(); SB0;
  // issue af01(0), bf_(0) from buf0
  af[0] = *(const short8*)(smem + aconst);
  af[1] = *(const short8*)(smem + aconst + 1024);
#pragma unroll
  for (int ni = 0; ni < 4; ++ni)
    bf_[ni] = *(const short8*)(smem + bconst + ni * 1024);

// Tile body. Entry: af[0..1](T), bf_(T) in regs; vm queue = stages T+1,T+2.
#define TILE_BODY(T, VMSTR, STAGE_, PREF_)                                   \
  do {                                                                       \
    const char* rb = smem + ((T) & 3) * 32768;                               \
    const char* rbn = smem + (((T) + 1) & 3) * 32768;                        \
    char* lb = smem + (((T) + 3) & 3) * 32768;                               \
    if (STAGE_) gload_lds16(gA, lb + ldA);                                   \
    af[2] = *(const short8*)(rb + aconst + 2048);                            \
    af[3] = *(const short8*)(rb + aconst + 3072);                            \
    SB0;                                                                     \
    __builtin_amdgcn_s_setprio(1);                                           \
    _Pragma("unroll")                                                        \
    for (int mi = 0; mi < 2; ++mi)                                           \
      _Pragma("unroll")                                                      \
      for (int ni = 0; ni < 4; ++ni)                                         \
        acc[mi][ni] = __builtin_amdgcn_mfma_f32_16x16x32_bf16(               \
            af[mi], bf_[ni], acc[mi][ni], 0, 0, 0);                          \
    __builtin_amdgcn_s_setprio(0);                                           \
    if (STAGE_) {                                                            \
      gload_lds16(gB, lb + ldB);                                             \
      gA += 32; gB += 32;                                                    \
    }                                                                        \
    asm volatile("s_waitcnt vmcnt(" VMSTR ")" ::: "memory");                 \
    asm volatile("s_waitcnt lgkmcnt(0)" ::: "memory");                       \
    __builtin_amdgcn_s_barrier(); SB0;                                       \
    if (PREF_) {                                                             \
      af[0] = *(const short8*)(rbn + aconst);                                \
      af[1] = *(const short8*)(rbn + aconst + 1024);                         \
    }                                                                        \
    SB0;                                                                     \
    __builtin_amdgcn_s_setprio(1);                                           \
    _Pragma("unroll")                                                        \
    for (int mi = 2; mi < 4; ++mi)                                           \
      _Pragma("unroll")                                                      \
      for (int ni = 0; ni < 4; ++ni)                                         \
        acc[mi][ni] = __builtin_amdgcn_mfma_f32_16x16x32_bf16(               \
            af[mi], bf_[ni], acc[mi][ni], 0, 0, 0);                          \
    __builtin_amdgcn_s_setprio(0);                                           \
    if (PREF_) {                                                             \
      _Pragma("unroll")                                                      \
      for (int ni = 0; ni < 4; ++ni)                                         \
        bf_[ni] = *(const short8*)(rbn + bconst + ni * 1024);                \
    }                                                                        \
  } while (0)

  for (int t = 0; t < NKT - 3; ++t) TILE_BODY(t, "4", true, true);
  TILE_BODY(NKT - 3, "2", false, true);
  TILE_BODY(NKT - 2, "0", false, true);
  TILE_BODY(NKT - 1, "0", false, false);
#undef TILE_BODY

  // ---- fused LSTM epilogue ----
  // Wave owns 64x64 gates (rows tm*256+wm*64+mi*16+[0,16), cols 16 j x 4 gates).
  // Wave-private LDS bounce, stride 68 floats (4608 B/wave; 16 waves = 73728 B,
  // disjoint from buf3 [98304,131072) which the final K-tile read).
  const int jw = fr;
  const int jg = tn * 64 + wn * 16 + jw;   // global j in [0,2048)
  const f32x4 bi = *(const f32x4*)(bias + tn * 256 + wn * 64 + jw * 4);
  float* ep = (float*)smem + wid * 1152;

#pragma unroll
  for (int mi = 0; mi < 4; ++mi) {
#pragma unroll
    for (int ni = 0; ni < 4; ++ni)
#pragma unroll
      for (int r = 0; r < 4; ++r)
        ep[(fq * 4 + r) * 68 + ni * 16 + fr] = acc[mi][ni][r];
    asm volatile("s_waitcnt lgkmcnt(0)" ::: "memory");
#pragma unroll
    for (int t4 = 0; t4 < 4; ++t4) {
      const int row = fq + t4 * 4;         // 0..15
      f32x4 g4 = *(const f32x4*)(ep + row * 68 + jw * 4);
      const float f_in = g4[0] + bi[0];
      const float i_in = g4[1] + bi[1];
      const float ic_in = g4[2] + bi[2];
      const float o_in = g4[3] + bi[3];
      const float ft = sigmoidf_(f_in);
      const float it = sigmoidf_(i_in);
      const float ics = __sinf(ic_in);
      const int mg = tm * 256 + wm * 64 + mi * 16 + row;
      const float cv = c[(size_t)mg * HDIM + jg];
      const float ct = cv * ft + ics * it;
      const float ot = sigmoidf_(o_in);
      const float ht = ot * __sinf(ct);
      out[(size_t)mg * HDIM + jg] = ht;
      out[OUT_HALF + (size_t)mg * HDIM + jg] = ct;
    }
    asm volatile("s_waitcnt lgkmcnt(0)" ::: "memory");
  }
}

extern "C" void kernel_launch(void* const* d_in, const int* in_sizes, int n_in,
                              void* d_out, int out_size, void* d_ws, size_t ws_size,
                              hipStream_t stream) {
  const float* x    = (const float*)d_in[0];
  const float* h    = (const float*)d_in[1];
  const float* c    = (const float*)d_in[2];
  const float* w_ih = (const float*)d_in[3];
  const float* w_hh = (const float*)d_in[4];
  const float* b_ih = (const float*)d_in[5];
  const float* b_hh = (const float*)d_in[6];
  float* out = (float*)d_out;

  char* ws = (char*)d_ws;
  unsigned short* Abf = (unsigned short*)ws;                       // 25,165,824 B
  unsigned short* Wbf = (unsigned short*)(ws + 25165824);          // 50,331,648 B
  float* bias = (float*)(ws + 25165824 + 50331648);                // 32,768 B

  hipFuncSetAttribute((const void*)lstm_gemm,
                      hipFuncAttributeMaxDynamicSharedMemorySize, 131072);

  pack_all<<<18432, 256, 0, stream>>>(x, h, w_ih, w_hh, b_ih, b_hh, Abf, Wbf, bias);
  lstm_gemm<<<512, 1024, 131072, stream>>>(Abf, Wbf, bias, c, out);
}